// Round 3
// baseline (78.986 us; speedup 1.0000x reference)
//
#include <hip/hip_runtime.h>
#include <cmath>

// Problem constants (match reference)
#define BB 4
#define NN 48
#define TT 33
#define RR 16
#define NC 80
#define NI 5
#define NEG (-1000.0f)

// chain_dp decomposition
#define XS 24    // x-range per block (x-split 2 -> 640 blocks)
#define XP 25    // padded stride for [k][x_local] LDS tiles
#define NTH 192  // threads per block = 96 tiles x 2 k-groups (3 waves)
#define NTILE 96 // thread-tiles per k-group (8 x-tiles x 12 y-tiles)

// ---------------------------------------------------------------------------
// Kernel 1: per-(b,c,x-half) tropical chain DP with 2-way split-k.
//   Each block: x-range of 24, all 48 y.  192 threads = 96 output tiles (3x4)
//   x 2 k-groups.  Each k-group computes a partial max over its 24 k's; the
//   partials are max-combined in LDS (max is associative).  Same again for
//   product 2, with the g1 partial round-tripped through LDS.
//   k-steps processed in pairs so fmax(acc,fmax(t0,t1)) -> v_max3_f32.
// ---------------------------------------------------------------------------
__global__ __launch_bounds__(NTH) void chain_dp_kernel(
    const float* __restrict__ trans,    // [B,N,N,T]
    const int*   __restrict__ rules,    // [Nc,3]
    const float* __restrict__ weights,  // [Nc]
    float*       __restrict__ sw)       // [B,Nc,N,N]
{
    __shared__ float H0T[NN * XP];   // A of product 1, [k][x_local], stride 25
    __shared__ float H1 [NN * NN];   // B of product 1, [k][y]
    __shared__ float H2 [NN * NN];   // B of product 2, [k][y]
    __shared__ float S1T[NN * XP];   // combined S1, [k2][x_local]
    __shared__ float Pa [NN * XP];   // g1 partial (P1); reused as P2 partial [j][tile]

    const int blk = blockIdx.x;          // 640 = 320 (b,c) x 2 x-halves
    const int bc  = blk >> 1;
    const int xh  = blk & 1;
    const int b   = bc / NC;
    const int c   = bc - b * NC;
    const int xbase = xh * XS;

    const int r0 = rules[c * 3 + 0];
    const int r1 = rules[c * 3 + 1];
    const int r2 = rules[c * 3 + 2];

    const float* tb = trans + (size_t)b * NN * NN * TT;

    // ---- stage: H0 x-slice (transposed, stride-25 writes: gcd(25,32)=1) ----
    for (int i = threadIdx.x; i < XS * NN; i += NTH) {
        const int xl = i / NN;
        const int k  = i - xl * NN;
        H0T[k * XP + xl] = tb[(size_t)((xbase + xl) * NN + k) * TT + r0];
    }
    // H1, H2 full (both products need all rows/cols of B)
    for (int i = threadIdx.x; i < NN * NN; i += NTH) {
        const size_t base = (size_t)i * TT;
        H1[i] = tb[base + r1];
        H2[i] = tb[base + r2];
    }
    __syncthreads();

    const int g  = threadIdx.x / NTILE;       // k-group 0/1
    const int w  = threadIdx.x - g * NTILE;   // tile id 0..95
    const int tx = w & 7;                     // 8 x-tiles (3 wide) = 24
    const int ty = w >> 3;                    // 12 y-tiles (4 wide) = 48
    const int x0 = tx * 3;
    const int y0 = ty * 4;
    const int k0 = g * 24;

    // ---- product 1 (partial over 24 k's) ----
    float acc[3][4];
    #pragma unroll
    for (int jx = 0; jx < 3; ++jx)
        #pragma unroll
        for (int jy = 0; jy < 4; ++jy) acc[jx][jy] = -INFINITY;

    #pragma unroll 4
    for (int kp = 0; kp < 12; ++kp) {
        const int k = k0 + kp * 2;
        float a0[3], a1[3];
        #pragma unroll
        for (int jx = 0; jx < 3; ++jx) {
            a0[jx] = H0T[k * XP + x0 + jx];
            a1[jx] = H0T[(k + 1) * XP + x0 + jx];
        }
        const float4 bv0 = *(const float4*)&H1[k * NN + y0];
        const float4 bv1 = *(const float4*)&H1[(k + 1) * NN + y0];
        const float b0[4] = {bv0.x, bv0.y, bv0.z, bv0.w};
        const float b1[4] = {bv1.x, bv1.y, bv1.z, bv1.w};
        #pragma unroll
        for (int jx = 0; jx < 3; ++jx)
            #pragma unroll
            for (int jy = 0; jy < 4; ++jy)
                acc[jx][jy] = fmaxf(acc[jx][jy],
                                    fmaxf(a0[jx] + b0[jy], a1[jx] + b1[jy]));
    }

    // partial store: g0 -> S1T, g1 -> Pa (same [k2][x_local] layout)
    {
        float* dst = (g == 0) ? S1T : Pa;
        #pragma unroll
        for (int jx = 0; jx < 3; ++jx)
            #pragma unroll
            for (int jy = 0; jy < 4; ++jy)
                dst[(y0 + jy) * XP + x0 + jx] = acc[jx][jy];
    }
    __syncthreads();

    // combine partials (pads carry garbage but are never read: x_local < 24)
    for (int j = threadIdx.x; j < NN * XP; j += NTH)
        S1T[j] = fmaxf(S1T[j], Pa[j]);
    __syncthreads();

    // ---- product 2 (partial over 24 k's) ----
    float acc2[3][4];
    #pragma unroll
    for (int jx = 0; jx < 3; ++jx)
        #pragma unroll
        for (int jy = 0; jy < 4; ++jy) acc2[jx][jy] = -INFINITY;

    #pragma unroll 4
    for (int kp = 0; kp < 12; ++kp) {
        const int k = k0 + kp * 2;
        float a0[3], a1[3];
        #pragma unroll
        for (int jx = 0; jx < 3; ++jx) {
            a0[jx] = S1T[k * XP + x0 + jx];
            a1[jx] = S1T[(k + 1) * XP + x0 + jx];
        }
        const float4 bv0 = *(const float4*)&H2[k * NN + y0];
        const float4 bv1 = *(const float4*)&H2[(k + 1) * NN + y0];
        const float b0[4] = {bv0.x, bv0.y, bv0.z, bv0.w};
        const float b1[4] = {bv1.x, bv1.y, bv1.z, bv1.w};
        #pragma unroll
        for (int jx = 0; jx < 3; ++jx)
            #pragma unroll
            for (int jy = 0; jy < 4; ++jy)
                acc2[jx][jy] = fmaxf(acc2[jx][jy],
                                     fmaxf(a0[jx] + b0[jy], a1[jx] + b1[jy]));
    }

    // g1 ships its partial via LDS: Pa2[j][tile] (lanes consecutive -> no conflicts)
    if (g == 1) {
        #pragma unroll
        for (int jx = 0; jx < 3; ++jx)
            #pragma unroll
            for (int jy = 0; jy < 4; ++jy)
                Pa[(jx * 4 + jy) * NTILE + w] = acc2[jx][jy];
    }
    __syncthreads();

    // epilogue (g0 only): final max, exp * weight, store
    if (g == 0) {
        const float wgt = weights[c];
        float* outp = sw + (size_t)bc * NN * NN;
        #pragma unroll
        for (int jx = 0; jx < 3; ++jx)
            #pragma unroll
            for (int jy = 0; jy < 4; ++jy) {
                const float m = fmaxf(acc2[jx][jy], Pa[(jx * 4 + jy) * NTILE + w]);
                outp[(xbase + x0 + jx) * NN + y0 + jy] = __expf(m) * wgt;
            }
    }
}

// ---------------------------------------------------------------------------
// Kernel 2: combine. 2 threads per (b,x,y) — each handles 8 triples.
// Lanes 0..127 of a block cover consecutive p (t-low half), lanes 128..255 the
// t-high half -> all sw reads stay fully coalesced within each wave.
// ---------------------------------------------------------------------------
__global__ __launch_bounds__(256) void combine_kernel(
    const float* __restrict__ sw,      // [B,Nc,N,N]
    const int*   __restrict__ mask,    // [B,N,N,R]
    const float* __restrict__ biases,  // [R]
    float*       __restrict__ out)     // [B,N,N,R]
{
    const int tq = threadIdx.x >> 7;                       // t-half 0/1
    const int pl = blockIdx.x * 128 + (threadIdx.x & 127); // (b,p) linear
    if (pl >= BB * NN * NN) return;
    const int b = pl / (NN * NN);
    const int p = pl - b * (NN * NN);

    const float* base = sw + (size_t)b * NC * NN * NN + p;

    float acc[8];
    #pragma unroll
    for (int tt = 0; tt < 8; ++tt) {
        const int t = tq * 8 + tt;
        float s = biases[t];
        #pragma unroll
        for (int i = 0; i < NI; ++i)
            s += base[(size_t)(t * NI + i) * NN * NN];
        acc[tt] = s;
    }

    const int4* m4 = (const int4*)(mask + (size_t)pl * RR + tq * 8);
    float4*     o4 = (float4*)(out + (size_t)pl * RR + tq * 8);
    #pragma unroll
    for (int q = 0; q < 2; ++q) {
        const int4 m = m4[q];
        float4 o;
        o.x = (m.x == 0) ? acc[q * 4 + 0] : NEG;
        o.y = (m.y == 0) ? acc[q * 4 + 1] : NEG;
        o.z = (m.z == 0) ? acc[q * 4 + 2] : NEG;
        o.w = (m.w == 0) ? acc[q * 4 + 3] : NEG;
        o4[q] = o;
    }
}

extern "C" void kernel_launch(void* const* d_in, const int* in_sizes, int n_in,
                              void* d_out, int out_size, void* d_ws, size_t ws_size,
                              hipStream_t stream)
{
    const float* trans   = (const float*)d_in[0];  // [B,N,N,T] f32
    const int*   mask    = (const int*)  d_in[1];  // [B,N,N,R] i32
    const int*   rules   = (const int*)  d_in[2];  // [Nc,3]    i32
    const float* weights = (const float*)d_in[3];  // [Nt,Ni]   f32
    const float* biases  = (const float*)d_in[4];  // [Nt]      f32
    float* out = (float*)d_out;
    float* sw  = (float*)d_ws;                     // [B,Nc,N,N] = 2.95 MB

    chain_dp_kernel<<<BB * NC * 2, NTH, 0, stream>>>(trans, rules, weights, sw);

    const int total2 = BB * NN * NN * 2;           // 2 threads per (b,p)
    combine_kernel<<<(total2 + 255) / 256, 256, 0, stream>>>(sw, mask, biases, out);
}

// Round 4
// 75.231 us; speedup vs baseline: 1.0499x; 1.0499x over previous
//
#include <hip/hip_runtime.h>
#include <cmath>

// Problem constants (match reference)
#define BB 4
#define NN 48
#define PP (NN * NN)   // 2304 (x,y) pairs per plane
#define NP 49          // padded row stride for transposed LDS tiles
#define TT 33
#define RR 16
#define NC 80
#define NI 5
#define NEG (-1000.0f)

// ---------------------------------------------------------------------------
// Kernel 0: transpose trans [B, 2304, 33] -> tpose [B, 33, 2304] so every
// hop-plane becomes a contiguous 9 KB block. LDS-tiled: coalesced float4
// reads, coalesced 64-wide writes; LDS read stride 33 words (gcd(33,32)=1,
// conflict-free).
// ---------------------------------------------------------------------------
__global__ __launch_bounds__(256) void transpose_kernel(
    const float* __restrict__ trans,   // [B, 2304, 33]
    float*       __restrict__ tpose)   // [B, 33, 2304]
{
    __shared__ float tile[64 * TT];    // 64 p x 33 t
    const int blk = blockIdx.x;        // B * 36
    const int b   = blk / 36;
    const int p0  = (blk - b * 36) * 64;

    const float4* src = (const float4*)(trans + ((size_t)b * PP + p0) * TT);
    for (int j = threadIdx.x; j < 64 * TT / 4; j += 256)
        ((float4*)tile)[j] = src[j];
    __syncthreads();

    for (int j = threadIdx.x; j < TT * 64; j += 256) {
        const int t  = j >> 6;
        const int pl = j & 63;
        tpose[((size_t)b * TT + t) * PP + p0 + pl] = tile[pl * TT + t];
    }
}

// ---------------------------------------------------------------------------
// Kernel 1: per-(b,c) tropical chain DP (R1-winner structure, coalesced
// staging from tpose).
//   H0T[k][x] (stride 49), H1[k][y], H2[k][y] staged via float4 loads.
//   S1 = H0 (x) H1,  S = S1 (x) H2  (max-plus), epilogue exp(S)*w.
//   192 threads = 16 x-tiles (3) x 12 y-tiles (4); 3x4 register tile each;
//   k-steps paired so fmax(acc, fmax(t0,t1)) folds to v_max3_f32.
// ---------------------------------------------------------------------------
__global__ __launch_bounds__(192) void chain_dp_kernel(
    const float* __restrict__ tpose,    // [B, 33, 2304]
    const int*   __restrict__ rules,    // [Nc,3]
    const float* __restrict__ weights,  // [Nc]
    float*       __restrict__ sw)       // [B,Nc,N,N]
{
    __shared__ float H0T[NN * NP];  // A of product 1, transposed [k][x]
    __shared__ float H1 [PP];       // B of product 1, [k][y]
    __shared__ float H2 [PP];       // B of product 2, [k][y]
    __shared__ float S1T[NN * NP];  // A of product 2, transposed [k][x]

    const int bc = blockIdx.x;
    const int b  = bc / NC;
    const int c  = bc - b * NC;

    const int r0 = rules[c * 3 + 0];
    const int r1 = rules[c * 3 + 1];
    const int r2 = rules[c * 3 + 2];

    const float* p0 = tpose + ((size_t)b * TT + r0) * PP;
    const float* p1 = tpose + ((size_t)b * TT + r1) * PP;
    const float* p2 = tpose + ((size_t)b * TT + r2) * PP;

    // Coalesced staging: 3 float4 per thread per plane. H0 is scattered into
    // the transposed tile (4 b32 writes, addr stride 196 words -> <=2-3-way
    // bank aliasing: free-ish per m136).
    for (int j = threadIdx.x; j < PP / 4; j += 192) {
        ((float4*)H1)[j] = ((const float4*)p1)[j];
        ((float4*)H2)[j] = ((const float4*)p2)[j];
        const float4 v0 = ((const float4*)p0)[j];
        const int x = (4 * j) / NN;
        const int k = (4 * j) - x * NN;   // 48 % 4 == 0: all 4 in one row
        H0T[(k + 0) * NP + x] = v0.x;
        H0T[(k + 1) * NP + x] = v0.y;
        H0T[(k + 2) * NP + x] = v0.z;
        H0T[(k + 3) * NP + x] = v0.w;
    }
    __syncthreads();

    const int tx = threadIdx.x & 15;   // 16 x-tiles
    const int ty = threadIdx.x >> 4;   // 12 y-tiles
    const int x0 = tx * 3;
    const int y0 = ty * 4;

    // ---- product 1: S1 = H0 (x) H1 ----
    float acc[3][4];
    #pragma unroll
    for (int jx = 0; jx < 3; ++jx)
        #pragma unroll
        for (int jy = 0; jy < 4; ++jy) acc[jx][jy] = -INFINITY;

    #pragma unroll 4
    for (int kp = 0; kp < NN / 2; ++kp) {
        const int k = kp * 2;
        float a0[3], a1[3];
        #pragma unroll
        for (int jx = 0; jx < 3; ++jx) {
            a0[jx] = H0T[k * NP + x0 + jx];
            a1[jx] = H0T[(k + 1) * NP + x0 + jx];
        }
        const float4 bv0 = *(const float4*)&H1[k * NN + y0];
        const float4 bv1 = *(const float4*)&H1[(k + 1) * NN + y0];
        const float b0[4] = {bv0.x, bv0.y, bv0.z, bv0.w};
        const float b1[4] = {bv1.x, bv1.y, bv1.z, bv1.w};
        #pragma unroll
        for (int jx = 0; jx < 3; ++jx)
            #pragma unroll
            for (int jy = 0; jy < 4; ++jy)
                acc[jx][jy] = fmaxf(acc[jx][jy],
                                    fmaxf(a0[jx] + b0[jy], a1[jx] + b1[jy]));
    }

    // S1T[y][x]: lanes step tx -> addr stride 3, gcd(3,32)=1 -> conflict-free
    #pragma unroll
    for (int jx = 0; jx < 3; ++jx)
        #pragma unroll
        for (int jy = 0; jy < 4; ++jy)
            S1T[(y0 + jy) * NP + x0 + jx] = acc[jx][jy];
    __syncthreads();

    // ---- product 2: S = S1 (x) H2, fused exp*weight epilogue ----
    float acc2[3][4];
    #pragma unroll
    for (int jx = 0; jx < 3; ++jx)
        #pragma unroll
        for (int jy = 0; jy < 4; ++jy) acc2[jx][jy] = -INFINITY;

    #pragma unroll 4
    for (int kp = 0; kp < NN / 2; ++kp) {
        const int k = kp * 2;
        float a0[3], a1[3];
        #pragma unroll
        for (int jx = 0; jx < 3; ++jx) {
            a0[jx] = S1T[k * NP + x0 + jx];
            a1[jx] = S1T[(k + 1) * NP + x0 + jx];
        }
        const float4 bv0 = *(const float4*)&H2[k * NN + y0];
        const float4 bv1 = *(const float4*)&H2[(k + 1) * NN + y0];
        const float b0[4] = {bv0.x, bv0.y, bv0.z, bv0.w};
        const float b1[4] = {bv1.x, bv1.y, bv1.z, bv1.w};
        #pragma unroll
        for (int jx = 0; jx < 3; ++jx)
            #pragma unroll
            for (int jy = 0; jy < 4; ++jy)
                acc2[jx][jy] = fmaxf(acc2[jx][jy],
                                     fmaxf(a0[jx] + b0[jy], a1[jx] + b1[jy]));
    }

    const float wgt = weights[c];
    float* outp = sw + (size_t)bc * PP;
    #pragma unroll
    for (int jx = 0; jx < 3; ++jx) {
        float4 o;
        o.x = __expf(acc2[jx][0]) * wgt;
        o.y = __expf(acc2[jx][1]) * wgt;
        o.z = __expf(acc2[jx][2]) * wgt;
        o.w = __expf(acc2[jx][3]) * wgt;
        *(float4*)&outp[(x0 + jx) * NN + y0] = o;
    }
}

// ---------------------------------------------------------------------------
// Kernel 2: combine. 2 threads per (b,x,y) — each handles 8 triples.
// All sw reads fully coalesced within each wave; mask/out via int4/float4.
// ---------------------------------------------------------------------------
__global__ __launch_bounds__(256) void combine_kernel(
    const float* __restrict__ sw,      // [B,Nc,N,N]
    const int*   __restrict__ mask,    // [B,N,N,R]
    const float* __restrict__ biases,  // [R]
    float*       __restrict__ out)     // [B,N,N,R]
{
    const int tq = threadIdx.x >> 7;                       // t-half 0/1
    const int pl = blockIdx.x * 128 + (threadIdx.x & 127); // (b,p) linear
    if (pl >= BB * PP) return;
    const int b = pl / PP;
    const int p = pl - b * PP;

    const float* base = sw + (size_t)b * NC * PP + p;

    float acc[8];
    #pragma unroll
    for (int tt = 0; tt < 8; ++tt) {
        const int t = tq * 8 + tt;
        float s = biases[t];
        #pragma unroll
        for (int i = 0; i < NI; ++i)
            s += base[(size_t)(t * NI + i) * PP];
        acc[tt] = s;
    }

    const int4* m4 = (const int4*)(mask + (size_t)pl * RR + tq * 8);
    float4*     o4 = (float4*)(out + (size_t)pl * RR + tq * 8);
    #pragma unroll
    for (int q = 0; q < 2; ++q) {
        const int4 m = m4[q];
        float4 o;
        o.x = (m.x == 0) ? acc[q * 4 + 0] : NEG;
        o.y = (m.y == 0) ? acc[q * 4 + 1] : NEG;
        o.z = (m.z == 0) ? acc[q * 4 + 2] : NEG;
        o.w = (m.w == 0) ? acc[q * 4 + 3] : NEG;
        o4[q] = o;
    }
}

extern "C" void kernel_launch(void* const* d_in, const int* in_sizes, int n_in,
                              void* d_out, int out_size, void* d_ws, size_t ws_size,
                              hipStream_t stream)
{
    const float* trans   = (const float*)d_in[0];  // [B,N,N,T] f32
    const int*   mask    = (const int*)  d_in[1];  // [B,N,N,R] i32
    const int*   rules   = (const int*)  d_in[2];  // [Nc,3]    i32
    const float* weights = (const float*)d_in[3];  // [Nt,Ni]   f32
    const float* biases  = (const float*)d_in[4];  // [Nt]      f32
    float* out = (float*)d_out;

    float* tpose = (float*)d_ws;                   // [B,33,2304] = 1.22 MB
    float* sw    = tpose + (size_t)BB * TT * PP;   // [B,Nc,48,48] = 2.95 MB

    transpose_kernel<<<BB * 36, 256, 0, stream>>>(trans, tpose);

    chain_dp_kernel<<<BB * NC, 192, 0, stream>>>(tpose, rules, weights, sw);

    const int total2 = BB * PP * 2;                // 2 threads per (b,p)
    combine_kernel<<<(total2 + 255) / 256, 256, 0, stream>>>(sw, mask, biases, out);
}